// Round 7
// baseline (345.532 us; speedup 1.0000x reference)
//
#include <hip/hip_runtime.h>
#include <hip/hip_bf16.h>

#define B_ 2048
#define L_ 200
#define D_ 256
#define K_ 8

typedef __attribute__((ext_vector_type(8))) _Float16 half8;
typedef __attribute__((ext_vector_type(4))) _Float16 half4v;
typedef __attribute__((ext_vector_type(4))) float f32x4;

#define USTP 24   // UsT row stride (f16): 16 data + 8 pad, 48 B (16B-aligned rows)
#define WP   232  // wH/wL row stride (f16)
#define CP   264  // cH/cL/Xs row stride (f16)

// LDS offsets (bytes)
#define OFF_UST0 0                        // UsT buf0 [256][24] f16 = 12288
#define OFF_UST1 12288                    // UsT buf1            = 12288
#define OFF_WH   24576                    // wH [16][232] f16    = 7424
#define OFF_WL   32000                    // wL [16][232] f16    = 7424
#define OFF_CH   39424                    // cH [16][264] f16    = 8448 (overlay XsA)
#define OFF_CL   47872                    // cL [16][264] f16    = 8448 (overlay XsB)
#define OFF_LB   56320                    // lb [8][200] f32     = 6400
#define OFF_RED  62720                    // red2 [16][8] f32    = 512
#define LDS_TOTAL 63232

// ------------------------------------------------------------------
// Kernel 0: W fp32 -> fp16
// ------------------------------------------------------------------
__global__ __launch_bounds__(256) void w_to_f16(const float* __restrict__ W,
                                                _Float16* __restrict__ Wh) {
    const int idx = (blockIdx.x * 256 + threadIdx.x) * 4;
    const float4 v = *(const float4*)(W + idx);
    half4v h = { (_Float16)v.x, (_Float16)v.y, (_Float16)v.z, (_Float16)v.w };
    *(half4v*)(Wh + idx) = h;
}

// ------------------------------------------------------------------
// Fused kernel, u fully register-resident after the prologue.
//  zf[7]  : z-pass B-frags, lane(fr,hi) holds u^T[16w+fr][32ks+8hi+j]
//  au[8]  : b-update A-frags (wave w<13), u[16w+fr][32d0+8hi+j]
//  UsT    : per-tile staging u^T[e][l-in-tile], double-buffered
// ------------------------------------------------------------------
__global__ __launch_bounds__(1024, 4) void fused_mie3(
        const float* __restrict__ X, const float* __restrict__ b_init,
        const int* __restrict__ mask, const _Float16* __restrict__ Wh,
        float* __restrict__ out) {
    extern __shared__ char dyn[];
    _Float16* UsT0 = (_Float16*)(dyn + OFF_UST0);
    _Float16* UsT1 = (_Float16*)(dyn + OFF_UST1);
    _Float16* wHs  = (_Float16*)(dyn + OFF_WH);
    _Float16* wLs  = (_Float16*)(dyn + OFF_WL);
    _Float16* cHs  = (_Float16*)(dyn + OFF_CH);
    _Float16* cLs  = (_Float16*)(dyn + OFF_CL);
    _Float16* XsA  = (_Float16*)(dyn + OFF_CH);  // prologue overlay
    _Float16* XsB  = (_Float16*)(dyn + OFF_CL);  // prologue overlay
    float* lb   = (float*)(dyn + OFF_LB);
    float* red2 = (float*)(dyn + OFF_RED);

    const int b = blockIdx.x;
    const int t = threadIdx.x;
    const int w = t >> 6, lane = t & 63;
    const int fr = lane & 15, hi = lane >> 4;

    // ---------- one-time init ----------
    if (t < 928) *(int4*)(dyn + OFF_WH + 16 * t) = make_int4(0, 0, 0, 0);
    for (int idx = t; idx < K_ * L_; idx += 1024) {
        const int k = idx / L_, l = idx - k * L_;
        lb[idx] = (mask[b * L_ + l] == 0) ? -1e9f
                                          : b_init[(size_t)b * (K_ * L_) + idx];
    }

    // hoisted W A-frags (wave w owns e = 16w..16w+15)
    half8 bw[8];
    {
        const _Float16* wr = Wh + (size_t)(16 * w + fr) * 256;
#pragma unroll
        for (int d0 = 0; d0 < 8; ++d0)
            bw[d0] = *(const half8*)(wr + 32 * d0 + 8 * hi);
    }

    // stage X tile 0 into XsA
    const float* Xb = X + (size_t)b * L_ * D_;
    const int sc4 = lane * 4;
    {
        const float4 v = *(const float4*)(Xb + w * 256 + sc4);
        half4v h = { (_Float16)v.x, (_Float16)v.y, (_Float16)v.z, (_Float16)v.w };
        *(half4v*)&XsA[w * CP + sc4] = h;
    }
    __syncthreads();

    // ---------- prologue: 13 l-tiles of 16, fully unrolled ----------
    half8 zf[7];
    zf[6] = (half8){ (_Float16)0, (_Float16)0, (_Float16)0, (_Float16)0,
                     (_Float16)0, (_Float16)0, (_Float16)0, (_Float16)0 };
    half8 au[8];

#pragma unroll
    for (int lt = 0; lt < 13; ++lt) {
        _Float16* xcur = (lt & 1) ? XsB : XsA;
        _Float16* xnxt = (lt & 1) ? XsA : XsB;
        _Float16* ucur = (lt & 1) ? UsT1 : UsT0;
        _Float16* uprv = (lt & 1) ? UsT0 : UsT1;

        // prefetch next X tile into regs (zeros past L)
        float4 xv = make_float4(0.f, 0.f, 0.f, 0.f);
        if (lt < 12) {
            const int l = 16 * (lt + 1) + w;
            if (l < L_) xv = *(const float4*)(Xb + l * 256 + sc4);
        }

        // u^T tile: D[e][l] = sum_d W[e,d] X[l,d]  (two indep. chains)
        f32x4 a1 = {}, a2 = {};
#pragma unroll
        for (int d0 = 0; d0 < 4; ++d0) {
            const half8 x8 = *(const half8*)&xcur[fr * CP + 32 * d0 + 8 * hi];
            a1 = __builtin_amdgcn_mfma_f32_16x16x32_f16(bw[d0], x8, a1, 0, 0, 0);
        }
#pragma unroll
        for (int d0 = 4; d0 < 8; ++d0) {
            const half8 x8 = *(const half8*)&xcur[fr * CP + 32 * d0 + 8 * hi];
            a2 = __builtin_amdgcn_mfma_f32_16x16x32_f16(bw[d0], x8, a2, 0, 0, 0);
        }

        // gather tile lt-1 from the previous buffer (overlaps this MFMA)
        if (lt > 0) {
            const int pt = lt - 1;
            if ((hi >> 1) == (pt & 1))
                zf[pt >> 1] = *(const half8*)&uprv[(16 * w + fr) * USTP + 8 * (hi & 1)];
            if (w == pt) {
#pragma unroll
                for (int d0 = 0; d0 < 8; ++d0) {
                    _Float16 tmp[8];
#pragma unroll
                    for (int j = 0; j < 8; ++j)
                        tmp[j] = uprv[(32 * d0 + 8 * hi + j) * USTP + fr];
                    au[d0] = *(half8*)tmp;
                }
            }
        }

        // write u^T C-frags: row e=16w+4hi+j, col r=fr
#pragma unroll
        for (int j = 0; j < 4; ++j)
            ucur[(16 * w + 4 * hi + j) * USTP + fr] = (_Float16)(a1[j] + a2[j]);

        // stage prefetched X tile
        if (lt < 12) {
            half4v h = { (_Float16)xv.x, (_Float16)xv.y, (_Float16)xv.z, (_Float16)xv.w };
            *(half4v*)&xnxt[w * CP + sc4] = h;
        }
        __syncthreads();
    }
    // final gather (tile 12, even -> buf0)
    {
        if ((hi >> 1) == 0)
            zf[6] = *(const half8*)&UsT0[(16 * w + fr) * USTP + 8 * (hi & 1)];
        if (w == 12) {
#pragma unroll
            for (int d0 = 0; d0 < 8; ++d0) {
                _Float16 tmp[8];
#pragma unroll
                for (int j = 0; j < 8; ++j)
                    tmp[j] = UsT0[(32 * d0 + 8 * hi + j) * USTP + fr];
                au[d0] = *(half8*)tmp;
            }
        }
    }

    // ---------- routing iterations ----------
    for (int iter = 0; iter < 3; ++iter) {
        // A. softmax over l (waves 0..7, wave = capsule k); hi/lo fp16 w
        if (t < 512) {
            const int k = t >> 6, ln = t & 63;
            float v[4];
            float m = -1e30f;
#pragma unroll
            for (int i = 0; i < 4; ++i) {
                const int l = ln + 64 * i;
                v[i] = (l < L_) ? lb[k * L_ + l] : -1e30f;
                m = fmaxf(m, v[i]);
            }
#pragma unroll
            for (int off = 32; off >= 1; off >>= 1)
                m = fmaxf(m, __shfl_xor(m, off));
            float e[4], s = 0.f;
#pragma unroll
            for (int i = 0; i < 4; ++i) {
                const int l = ln + 64 * i;
                e[i] = (l < L_) ? __expf(v[i] - m) : 0.f;
                s += e[i];
            }
#pragma unroll
            for (int off = 32; off >= 1; off >>= 1)
                s += __shfl_xor(s, off);
            const float rinv = 1.0f / s;
#pragma unroll
            for (int i = 0; i < 4; ++i) {
                const int l = ln + 64 * i;
                if (l < L_) {
                    const float wv = e[i] * rinv;
                    const _Float16 h = (_Float16)wv;
                    wHs[k * WP + l] = h;
                    wLs[k * WP + l] = (_Float16)(wv - (float)h);
                }
            }
        }
        __syncthreads();

        // B. z-pass MFMA: B-frags from zf regs, A-frags wH/wL from LDS
        f32x4 zH = {}, zL = {};
#pragma unroll
        for (int ks = 0; ks < 7; ++ks) {
            const half8 ah = *(const half8*)&wHs[fr * WP + 32 * ks + 8 * hi];
            const half8 al = *(const half8*)&wLs[fr * WP + 32 * ks + 8 * hi];
            zH = __builtin_amdgcn_mfma_f32_16x16x32_f16(ah, zf[ks], zH, 0, 0, 0);
            zL = __builtin_amdgcn_mfma_f32_16x16x32_f16(al, zf[ks], zL, 0, 0, 0);
        }
        const float z0 = zH[0] + zL[0], z1 = zH[1] + zL[1];
        const float z2 = zH[2] + zL[2], z3 = zH[3] + zL[3];

        // C. norms: reduce z^2 over fr (16-lane groups)
        float sq0 = z0 * z0, sq1 = z1 * z1, sq2 = z2 * z2, sq3 = z3 * z3;
#pragma unroll
        for (int off = 1; off <= 8; off <<= 1) {
            sq0 += __shfl_xor(sq0, off);
            sq1 += __shfl_xor(sq1, off);
            sq2 += __shfl_xor(sq2, off);
            sq3 += __shfl_xor(sq3, off);
        }
        if (fr == 0 && hi < 2) {
            f32x4 sv = { sq0, sq1, sq2, sq3 };
            *(f32x4*)&red2[w * 8 + 4 * hi] = sv;
        }
        __syncthreads();

        // D. squash scale, computed redundantly per wave (no extra barrier)
        float myscale = 0.f;
        if (lane < 8) {
            float ns = 0.f;
#pragma unroll
            for (int ww = 0; ww < 16; ++ww) ns += red2[ww * 8 + lane];
            myscale = ns / ((1.f + ns) * sqrtf(ns + 1e-8f));
        }
        const float sc0 = __shfl(myscale, 4 * hi + 0);
        const float sc1 = __shfl(myscale, 4 * hi + 1);
        const float sc2 = __shfl(myscale, 4 * hi + 2);
        const float sc3 = __shfl(myscale, 4 * hi + 3);

        // E. emit c (hi/lo) or final output
        if (iter == 2) {
            if (hi < 2) {
                float* op = out + (size_t)b * (K_ * D_) + (4 * hi) * D_ + 16 * w + fr;
                op[0 * D_] = sc0 * z0;
                op[1 * D_] = sc1 * z1;
                op[2 * D_] = sc2 * z2;
                op[3 * D_] = sc3 * z3;
            }
        } else {
            if (hi < 2) {
                const float v0 = sc0 * z0, v1 = sc1 * z1;
                const float v2 = sc2 * z2, v3 = sc3 * z3;
                const _Float16 h0 = (_Float16)v0, h1 = (_Float16)v1;
                const _Float16 h2 = (_Float16)v2, h3 = (_Float16)v3;
                const int cb = 16 * w + fr;
                cHs[(4 * hi + 0) * CP + cb] = h0;
                cHs[(4 * hi + 1) * CP + cb] = h1;
                cHs[(4 * hi + 2) * CP + cb] = h2;
                cHs[(4 * hi + 3) * CP + cb] = h3;
                cLs[(4 * hi + 0) * CP + cb] = (_Float16)(v0 - (float)h0);
                cLs[(4 * hi + 1) * CP + cb] = (_Float16)(v1 - (float)h1);
                cLs[(4 * hi + 2) * CP + cb] = (_Float16)(v2 - (float)h2);
                cLs[(4 * hi + 3) * CP + cb] = (_Float16)(v3 - (float)h3);
            }
            __syncthreads();

            // F. b-update MFMA: A = au regs, B = cH/cL LDS (two chains)
            if (w < 13) {
                f32x4 dH = {}, dL = {};
#pragma unroll
                for (int d0 = 0; d0 < 8; ++d0) {
                    const half8 bh = *(const half8*)&cHs[fr * CP + 32 * d0 + 8 * hi];
                    const half8 bl = *(const half8*)&cLs[fr * CP + 32 * d0 + 8 * hi];
                    dH = __builtin_amdgcn_mfma_f32_16x16x32_f16(au[d0], bh, dH, 0, 0, 0);
                    dL = __builtin_amdgcn_mfma_f32_16x16x32_f16(au[d0], bl, dL, 0, 0, 0);
                }
                if (fr < 8) {
#pragma unroll
                    for (int j = 0; j < 4; ++j) {
                        const int l = 16 * w + 4 * hi + j;
                        if (l < L_) lb[fr * L_ + l] += dH[j] + dL[j];
                    }
                }
            }
            __syncthreads();
        }
    }
}

// ==================================================================
extern "C" void kernel_launch(void* const* d_in, const int* in_sizes, int n_in,
                              void* d_out, int out_size, void* d_ws, size_t ws_size,
                              hipStream_t stream) {
    (void)in_sizes; (void)n_in; (void)out_size; (void)ws_size;
    const float* behavior = (const float*)d_in[0];   // [B, L, D]
    const float* W        = (const float*)d_in[1];   // [D, D]
    const float* b_init   = (const float*)d_in[2];   // [B, K, L]
    const int*   mask     = (const int*)d_in[3];     // [B, L]
    float* out      = (float*)d_out;                 // [B, K, D]
    _Float16* Wh    = (_Float16*)d_ws;               // [256,256] fp16

    hipFuncSetAttribute((const void*)fused_mie3,
                        hipFuncAttributeMaxDynamicSharedMemorySize, LDS_TOTAL);

    w_to_f16<<<64, 256, 0, stream>>>(W, Wh);
    fused_mie3<<<B_, 1024, LDS_TOTAL, stream>>>(behavior, b_init, mask, Wh, out);
}

// Round 8
// 261.004 us; speedup vs baseline: 1.3239x; 1.3239x over previous
//
#include <hip/hip_runtime.h>
#include <hip/hip_bf16.h>

#define B_ 2048
#define L_ 200
#define D_ 256
#define K_ 8

typedef __attribute__((ext_vector_type(8))) _Float16 half8;
typedef __attribute__((ext_vector_type(4))) _Float16 half4v;
typedef __attribute__((ext_vector_type(4))) float f32x4;

// f16-element strides (bank-spread checked mod-32 in dwords)
#define LTP 232   // ut_T row stride (cols=l; data 0..207, zeros 208..231)
#define WP  232   // wH/wL row stride
#define CP  264   // cH/cL/Xs row stride

// LDS offsets (bytes), all 16B-aligned.  Total kept >81920 B deliberately:
// 1 block/CU (LDS-pinned) => backend budgets 128 VGPRs => zf/au stay in regs.
#define OFF_UTT  0                       // ut_T [256][232] f16 = 118784
#define OFF_WH   118784                  // wH   [16][232]  f16 = 7424
#define OFF_WL   126208                  // wL   [16][232]  f16 = 7424
#define OFF_XA   133632                  // XsA  [16][264]  f16 = 8448  (overlay: cH)
#define OFF_XB   142080                  // XsB  [16][264]  f16 = 8448  (overlay: cL)
#define OFF_LB   150528                  // lb   [8][200]   f32 = 6400
#define OFF_RED  156928                  // red2 [16][8]    f32 = 512
#define LDS_TOTAL 157472                 // < 163840

// ------------------------------------------------------------------
// Kernel 0: W fp32 -> fp16
// ------------------------------------------------------------------
__global__ __launch_bounds__(256) void w_to_f16(const float* __restrict__ W,
                                                _Float16* __restrict__ Wh) {
    const int idx = (blockIdx.x * 256 + threadIdx.x) * 4;
    const float4 v = *(const float4*)(W + idx);
    half4v h = { (_Float16)v.x, (_Float16)v.y, (_Float16)v.z, (_Float16)v.w };
    *(half4v*)(Wh + idx) = h;
}

// ------------------------------------------------------------------
// Fused kernel: one block (1024 thr, 16 waves) per batch.
// Prologue: u^T = W@X^T via swapped-operand MFMA -> utT (LDS).
// Post-prologue one-time gathers: zf[7] (z-pass B-frags) and au[8]
// (b-update A-frags) into registers; iterations never re-read utT.
// ------------------------------------------------------------------
__global__ __launch_bounds__(1024, 4) void fused_mie4(
        const float* __restrict__ X, const float* __restrict__ b_init,
        const int* __restrict__ mask, const _Float16* __restrict__ Wh,
        float* __restrict__ out) {
    extern __shared__ char dyn[];
    _Float16* utT = (_Float16*)(dyn + OFF_UTT);
    _Float16* wHs = (_Float16*)(dyn + OFF_WH);
    _Float16* wLs = (_Float16*)(dyn + OFF_WL);
    _Float16* XsA = (_Float16*)(dyn + OFF_XA);
    _Float16* XsB = (_Float16*)(dyn + OFF_XB);
    _Float16* cHs = (_Float16*)(dyn + OFF_XA);   // routing overlay
    _Float16* cLs = (_Float16*)(dyn + OFF_XB);   // routing overlay
    float* lb   = (float*)(dyn + OFF_LB);
    float* red2 = (float*)(dyn + OFF_RED);

    const int b = blockIdx.x;
    const int t = threadIdx.x;
    const int w = t >> 6, lane = t & 63;
    const int fr = lane & 15, hi = lane >> 4;

    // ---------- one-time init ----------
    {   // zero ut_T pad cols 200..231 (MFMA K-padding)
        const int row = t >> 2, part = t & 3;
        *(int4*)&utT[row * LTP + 200 + 8 * part] = make_int4(0, 0, 0, 0);
    }
    // zero wH/wL fully (rows k>=8, cols l>=200 stay zero forever)
    if (t < 928) *(int4*)(dyn + OFF_WH + 16 * t) = make_int4(0, 0, 0, 0);
    // init logits with mask
    for (int idx = t; idx < K_ * L_; idx += 1024) {
        const int k = idx / L_, l = idx - k * L_;
        lb[idx] = (mask[b * L_ + l] == 0) ? -1e9f
                                          : b_init[(size_t)b * (K_ * L_) + idx];
    }

    // hoisted W frags -> MFMA A operand (wave w owns e = 16w..16w+15)
    half8 bw[8];
    {
        const _Float16* wr = Wh + (size_t)(16 * w + fr) * 256;
#pragma unroll
        for (int d0 = 0; d0 < 8; ++d0)
            bw[d0] = *(const half8*)(wr + 32 * d0 + 8 * hi);
    }

    // stage X tile 0 (rows 0..15) into XsA
    const float* Xb = X + (size_t)b * L_ * D_;
    const int sc4 = lane * 4;
    {
        const float4 v = *(const float4*)(Xb + w * 256 + sc4);
        half4v h = { (_Float16)v.x, (_Float16)v.y, (_Float16)v.z, (_Float16)v.w };
        *(half4v*)&XsA[w * CP + sc4] = h;
    }
    __syncthreads();

    // ---------- prologue: 13 l-tiles, double-buffered, 1 barrier/tile ----------
    for (int lt = 0; lt < 13; ++lt) {
        _Float16* cur = (lt & 1) ? XsB : XsA;
        _Float16* nxt = (lt & 1) ? XsA : XsB;
        // prefetch next X tile into regs (zeros past L)
        float4 xv = make_float4(0.f, 0.f, 0.f, 0.f);
        if (lt < 12) {
            const int l = 16 * (lt + 1) + w;
            if (l < L_) xv = *(const float4*)(Xb + l * 256 + sc4);
        }
        // u^T tile via swapped MFMA: D[e][l] = sum_d W[e,d] X[l,d]
        f32x4 acc = {};
#pragma unroll
        for (int d0 = 0; d0 < 8; ++d0) {
            const half8 a8 = *(const half8*)&cur[fr * CP + 32 * d0 + 8 * hi];
            acc = __builtin_amdgcn_mfma_f32_16x16x32_f16(bw[d0], a8, acc, 0, 0, 0);
        }
        // write C-frag straight into utT: row e=16w+4hi+j, col l=16lt+fr
#pragma unroll
        for (int j = 0; j < 4; ++j)
            utT[(16 * w + 4 * hi + j) * LTP + 16 * lt + fr] = (_Float16)acc[j];
        // stage prefetched tile into the other buffer
        if (lt < 12) {
            half4v h = { (_Float16)xv.x, (_Float16)xv.y, (_Float16)xv.z, (_Float16)xv.w };
            *(half4v*)&nxt[w * CP + sc4] = h;
        }
        __syncthreads();
    }

    // ---------- one-time register gathers (utT is dead afterwards) ----------
    // z-pass B-frags: lane(fr,hi) holds u^T[16w+fr][32ks+8hi .. +7]
    half8 zf[7];
#pragma unroll
    for (int ks = 0; ks < 7; ++ks)
        zf[ks] = *(const half8*)&utT[(16 * w + fr) * LTP + 32 * ks + 8 * hi];
    // b-update A-frags: wave w<13 holds u rows 16w..16w+15, d-contig
    half8 au[8];
    if (w < 13) {
#pragma unroll
        for (int d0 = 0; d0 < 8; ++d0) {
            _Float16 tmp[8];
#pragma unroll
            for (int j = 0; j < 8; ++j)
                tmp[j] = utT[(32 * d0 + 8 * hi + j) * LTP + 16 * w + fr];
            au[d0] = *(half8*)tmp;
        }
    }

    // ---------- routing iterations ----------
    for (int iter = 0; iter < 3; ++iter) {
        // A. softmax over l (waves 0..7, wave = capsule k); hi/lo fp16 w
        if (t < 512) {
            const int k = t >> 6, ln = t & 63;
            float v[4];
            float m = -1e30f;
#pragma unroll
            for (int i = 0; i < 4; ++i) {
                const int l = ln + 64 * i;
                v[i] = (l < L_) ? lb[k * L_ + l] : -1e30f;
                m = fmaxf(m, v[i]);
            }
#pragma unroll
            for (int off = 32; off >= 1; off >>= 1)
                m = fmaxf(m, __shfl_xor(m, off));
            float e[4], s = 0.f;
#pragma unroll
            for (int i = 0; i < 4; ++i) {
                const int l = ln + 64 * i;
                e[i] = (l < L_) ? __expf(v[i] - m) : 0.f;
                s += e[i];
            }
#pragma unroll
            for (int off = 32; off >= 1; off >>= 1)
                s += __shfl_xor(s, off);
            const float rinv = 1.0f / s;
#pragma unroll
            for (int i = 0; i < 4; ++i) {
                const int l = ln + 64 * i;
                if (l < L_) {
                    const float wv = e[i] * rinv;
                    const _Float16 h = (_Float16)wv;
                    wHs[k * WP + l] = h;
                    wLs[k * WP + l] = (_Float16)(wv - (float)h);
                }
            }
        }
        __syncthreads();

        // B. z-pass MFMA: A = wH/wL (LDS), B = zf (regs); two chains
        f32x4 zH = {}, zL = {};
#pragma unroll
        for (int ks = 0; ks < 7; ++ks) {
            const half8 ah = *(const half8*)&wHs[fr * WP + 32 * ks + 8 * hi];
            const half8 al = *(const half8*)&wLs[fr * WP + 32 * ks + 8 * hi];
            zH = __builtin_amdgcn_mfma_f32_16x16x32_f16(ah, zf[ks], zH, 0, 0, 0);
            zL = __builtin_amdgcn_mfma_f32_16x16x32_f16(al, zf[ks], zL, 0, 0, 0);
        }
        const float z0 = zH[0] + zL[0], z1 = zH[1] + zL[1];
        const float z2 = zH[2] + zL[2], z3 = zH[3] + zL[3];

        // C. norms: reduce z^2 over fr (16-lane groups), stash in red2
        float sq0 = z0 * z0, sq1 = z1 * z1, sq2 = z2 * z2, sq3 = z3 * z3;
#pragma unroll
        for (int off = 1; off <= 8; off <<= 1) {
            sq0 += __shfl_xor(sq0, off);
            sq1 += __shfl_xor(sq1, off);
            sq2 += __shfl_xor(sq2, off);
            sq3 += __shfl_xor(sq3, off);
        }
        if (fr == 0 && hi < 2) {
            f32x4 sv = { sq0, sq1, sq2, sq3 };
            *(f32x4*)&red2[w * 8 + 4 * hi] = sv;
        }
        __syncthreads();

        // D. squash scale, redundant per wave + shfl broadcast (no 2nd barrier)
        float myscale = 0.f;
        if (lane < 8) {
            float ns = 0.f;
#pragma unroll
            for (int ww = 0; ww < 16; ++ww) ns += red2[ww * 8 + lane];
            myscale = ns / ((1.f + ns) * sqrtf(ns + 1e-8f));
        }
        const float sc0 = __shfl(myscale, 4 * hi + 0);
        const float sc1 = __shfl(myscale, 4 * hi + 1);
        const float sc2 = __shfl(myscale, 4 * hi + 2);
        const float sc3 = __shfl(myscale, 4 * hi + 3);

        // E. emit c (hi/lo fp16) or final output
        if (iter == 2) {
            if (hi < 2) {
                float* op = out + (size_t)b * (K_ * D_) + (4 * hi) * D_ + 16 * w + fr;
                op[0 * D_] = sc0 * z0;
                op[1 * D_] = sc1 * z1;
                op[2 * D_] = sc2 * z2;
                op[3 * D_] = sc3 * z3;
            }
        } else {
            if (hi < 2) {
                const float v0 = sc0 * z0, v1 = sc1 * z1;
                const float v2 = sc2 * z2, v3 = sc3 * z3;
                const _Float16 h0 = (_Float16)v0, h1 = (_Float16)v1;
                const _Float16 h2 = (_Float16)v2, h3 = (_Float16)v3;
                const int cb = 16 * w + fr;
                cHs[(4 * hi + 0) * CP + cb] = h0;
                cHs[(4 * hi + 1) * CP + cb] = h1;
                cHs[(4 * hi + 2) * CP + cb] = h2;
                cHs[(4 * hi + 3) * CP + cb] = h3;
                cLs[(4 * hi + 0) * CP + cb] = (_Float16)(v0 - (float)h0);
                cLs[(4 * hi + 1) * CP + cb] = (_Float16)(v1 - (float)h1);
                cLs[(4 * hi + 2) * CP + cb] = (_Float16)(v2 - (float)h2);
                cLs[(4 * hi + 3) * CP + cb] = (_Float16)(v3 - (float)h3);
            }
            __syncthreads();

            // F. b-update MFMA: A = au regs, B = cH/cL LDS (two chains)
            if (w < 13) {
                f32x4 dH = {}, dL = {};
#pragma unroll
                for (int d0 = 0; d0 < 8; ++d0) {
                    const half8 bh = *(const half8*)&cHs[fr * CP + 32 * d0 + 8 * hi];
                    const half8 bl = *(const half8*)&cLs[fr * CP + 32 * d0 + 8 * hi];
                    dH = __builtin_amdgcn_mfma_f32_16x16x32_f16(au[d0], bh, dH, 0, 0, 0);
                    dL = __builtin_amdgcn_mfma_f32_16x16x32_f16(au[d0], bl, dL, 0, 0, 0);
                }
                if (fr < 8) {
#pragma unroll
                    for (int j = 0; j < 4; ++j) {
                        const int l = 16 * w + 4 * hi + j;
                        if (l < L_) lb[fr * L_ + l] += dH[j] + dL[j];
                    }
                }
            }
            __syncthreads();
        }
    }
}

// ==================================================================
extern "C" void kernel_launch(void* const* d_in, const int* in_sizes, int n_in,
                              void* d_out, int out_size, void* d_ws, size_t ws_size,
                              hipStream_t stream) {
    (void)in_sizes; (void)n_in; (void)out_size; (void)ws_size;
    const float* behavior = (const float*)d_in[0];   // [B, L, D]
    const float* W        = (const float*)d_in[1];   // [D, D]
    const float* b_init   = (const float*)d_in[2];   // [B, K, L]
    const int*   mask     = (const int*)d_in[3];     // [B, L]
    float* out      = (float*)d_out;                 // [B, K, D]
    _Float16* Wh    = (_Float16*)d_ws;               // [256,256] fp16

    hipFuncSetAttribute((const void*)fused_mie4,
                        hipFuncAttributeMaxDynamicSharedMemorySize, LDS_TOTAL);

    w_to_f16<<<64, 256, 0, stream>>>(W, Wh);
    fused_mie4<<<B_, 1024, LDS_TOTAL, stream>>>(behavior, b_init, mask, Wh, out);
}